// Round 4
// baseline (809.508 us; speedup 1.0000x reference)
//
#include <hip/hip_runtime.h>
#include <math.h>

#define NB 1024   // batch
#define NBLK 784  // grid size; 4 blocks/CU capacity (launch_bounds 256,4) >= 784 -> all co-resident

// ---------------------------------------------------------------------------
// Zero the grid-barrier counters (first graph node, runs every replay).
// ---------------------------------------------------------------------------
__global__ void k_zero(unsigned* bar) {
  if (threadIdx.x < 16) bar[threadIdx.x] = 0u;
}

// ---------------------------------------------------------------------------
// Software grid barrier: all NBLK blocks co-resident (capacity arithmetic
// above). Single-use counter per barrier instance (no ABA). Agent-scope
// release/acquire fences handle cross-XCD L2 visibility (guide G16).
// ---------------------------------------------------------------------------
__device__ __forceinline__ void gbar(unsigned* ctr) {
  __syncthreads();                 // all block waves done (+vmcnt drained)
  if (threadIdx.x == 0) {
    __threadfence();               // release: flush this XCD's L2
    __hip_atomic_fetch_add(ctr, 1u, __ATOMIC_ACQ_REL, __HIP_MEMORY_SCOPE_AGENT);
    while (__hip_atomic_load(ctr, __ATOMIC_ACQUIRE, __HIP_MEMORY_SCOPE_AGENT) < NBLK)
      __builtin_amdgcn_s_sleep(2);
    __threadfence();               // acquire: invalidate L1/L2 before reads
  }
  __syncthreads();
}

// ---------------------------------------------------------------------------
// Whole net in one kernel, phases separated by grid barriers.
//   P0 transpose  x(B,3072) -> xT(3072,B)            768 units
//   P1 conv1+relu+pool  -> h1(6,14,14,B)             784 units (196 pos x 4 bg)
//   P2 conv2+relu+pool  -> h2(16,5,5,B)              400 units
//   P3 conv3(GEMM k=400)+relu -> h3(120,B)           480 units
//   P4 fc2+relu -> h4(84,B)                          336 units
//   P5 fc3 -> out(B,10)                               48 units
// ---------------------------------------------------------------------------
__global__ __launch_bounds__(256, 4) void k_all(
    const float* __restrict__ x,
    const float* __restrict__ w1, const float* __restrict__ b1,
    const float* __restrict__ w2, const float* __restrict__ b2,
    const float* __restrict__ w3, const float* __restrict__ b3,
    const float* __restrict__ fc2w, const float* __restrict__ fc2b,
    const float* __restrict__ fc3w, const float* __restrict__ fc3b,
    float* __restrict__ out,
    float* __restrict__ xT, float* __restrict__ h1, float* __restrict__ h2,
    float* __restrict__ h3, float* __restrict__ h4, unsigned* bar) {
  __shared__ __align__(16) float smem[64 * 65];  // 16.6 KB, aliased per phase
  const int tid = threadIdx.x;
  const int u = blockIdx.x;

  // ---------------- P0: transpose ----------------
  if (u < 768) {
    const int c0 = (u % 48) * 64, b0 = (u / 48) * 64;
    const int tx = tid & 63, ty = tid >> 6;
    float(*tile)[65] = (float(*)[65])smem;
#pragma unroll
    for (int r = 0; r < 16; ++r) {
      const int bb = r * 4 + ty;
      tile[bb][tx] = x[(size_t)(b0 + bb) * 3072 + c0 + tx];
    }
    __syncthreads();
#pragma unroll
    for (int r = 0; r < 16; ++r) {
      const int cc = r * 4 + ty;
      xT[(size_t)(c0 + cc) * NB + b0 + tx] = tile[tx][cc];
    }
  }
  gbar(bar + 0);

  // ---------------- P1: conv1 + bias + relu + pool ----------------
  {
    const int pos = u % 196, bg = u / 196;
    const int ph = pos / 14, pw = pos % 14;
    const int b = bg * 256 + tid;
    float* wL = smem;          // 72 chunks of 25, padded to 28 = 2016 f
    float* bL = smem + 2016;   // 24 f
    for (int t = tid; t < 72 * 25; t += 256) {
      const int chunk = t / 25, p = t - chunk * 25;
      const int o = chunk / 12, rem = chunk - o * 12;
      const int c = rem >> 2, i = (rem >> 1) & 1, j = rem & 1;
      wL[chunk * 28 + p] =
          w1[((size_t)((o * 3 + c) * 28 + (2 * ph + i)) * 28 + (2 * pw + j)) * 25 + p];
    }
    if (tid < 24) {
      const int o = tid >> 2, i = (tid >> 1) & 1, j = tid & 1;
      bL[tid] = b1[(size_t)(o * 28 + (2 * ph + i)) * 28 + (2 * pw + j)];
    }
    __syncthreads();

    float acc[6][2][2];
#pragma unroll
    for (int o = 0; o < 6; ++o)
#pragma unroll
      for (int i = 0; i < 2; ++i)
#pragma unroll
        for (int j = 0; j < 2; ++j) acc[o][i][j] = 0.f;

    for (int c = 0; c < 3; ++c) {
      float xw[6][6];
#pragma unroll
      for (int dh = 0; dh < 6; ++dh)
#pragma unroll
        for (int dw = 0; dw < 6; ++dw)
          xw[dh][dw] =
              xT[((size_t)(c * 32 + (2 * ph + dh)) * 32 + (2 * pw + dw)) * NB + b];
#pragma unroll
      for (int o = 0; o < 6; ++o)
#pragma unroll
        for (int i = 0; i < 2; ++i)
#pragma unroll
          for (int j = 0; j < 2; ++j) {
            const float* wp = &wL[((o * 3 + c) * 4 + i * 2 + j) * 28];
#pragma unroll
            for (int p = 0; p < 25; ++p)
              acc[o][i][j] = fmaf(xw[i + p / 5][j + p % 5], wp[p], acc[o][i][j]);
          }
    }

#pragma unroll
    for (int o = 0; o < 6; ++o) {
      float v[2][2];
#pragma unroll
      for (int i = 0; i < 2; ++i)
#pragma unroll
        for (int j = 0; j < 2; ++j)
          v[i][j] = fmaxf(acc[o][i][j] + bL[o * 4 + i * 2 + j], 0.f);
      const float m = fmaxf(fmaxf(v[0][0], v[0][1]), fmaxf(v[1][0], v[1][1]));
      h1[((size_t)(o * 14 + ph) * 14 + pw) * NB + b] = m;
    }
  }
  gbar(bar + 1);

  // ---------------- P2: conv2 + bias + relu + pool ----------------
  if (u < 400) {
    const int pos = u % 25;
    const int og = (u / 25) % 4, bg = u / 100;
    const int ph = pos / 5, pw = pos % 5;
    const int b = bg * 256 + tid;
    float* wL = smem;          // 96 chunks of 25, padded to 28 = 2688 f
    float* bL = smem + 2688;   // 16 f
    for (int t = tid; t < 96 * 25; t += 256) {
      const int chunk = t / 25, p = t - chunk * 25;
      const int oo = chunk / 24, rem = chunk - oo * 24;
      const int c = rem >> 2, i = (rem >> 1) & 1, j = rem & 1;
      const int o = og * 4 + oo;
      wL[chunk * 28 + p] =
          w2[((size_t)((o * 6 + c) * 10 + (2 * ph + i)) * 10 + (2 * pw + j)) * 25 + p];
    }
    if (tid < 16) {
      const int oo = tid >> 2, i = (tid >> 1) & 1, j = tid & 1;
      const int o = og * 4 + oo;
      bL[tid] = b2[(size_t)(o * 10 + (2 * ph + i)) * 10 + (2 * pw + j)];
    }
    __syncthreads();

    float acc[4][2][2];
#pragma unroll
    for (int oo = 0; oo < 4; ++oo)
#pragma unroll
      for (int i = 0; i < 2; ++i)
#pragma unroll
        for (int j = 0; j < 2; ++j) acc[oo][i][j] = 0.f;

    for (int c = 0; c < 6; ++c) {
      float xw[6][6];
#pragma unroll
      for (int dh = 0; dh < 6; ++dh)
#pragma unroll
        for (int dw = 0; dw < 6; ++dw)
          xw[dh][dw] =
              h1[((size_t)(c * 14 + (2 * ph + dh)) * 14 + (2 * pw + dw)) * NB + b];
#pragma unroll
      for (int oo = 0; oo < 4; ++oo)
#pragma unroll
        for (int i = 0; i < 2; ++i)
#pragma unroll
          for (int j = 0; j < 2; ++j) {
            const float* wp = &wL[((oo * 6 + c) * 4 + i * 2 + j) * 28];
#pragma unroll
            for (int p = 0; p < 25; ++p)
              acc[oo][i][j] = fmaf(xw[i + p / 5][j + p % 5], wp[p], acc[oo][i][j]);
          }
    }

#pragma unroll
    for (int oo = 0; oo < 4; ++oo) {
      const int o = og * 4 + oo;
      float v[2][2];
#pragma unroll
      for (int i = 0; i < 2; ++i)
#pragma unroll
        for (int j = 0; j < 2; ++j)
          v[i][j] = fmaxf(acc[oo][i][j] + bL[oo * 4 + i * 2 + j], 0.f);
      const float m = fmaxf(fmaxf(v[0][0], v[0][1]), fmaxf(v[1][0], v[1][1]));
      h2[((size_t)(o * 5 + ph) * 5 + pw) * NB + b] = m;
    }
  }
  gbar(bar + 2);

  // ---------------- P3: conv3 (GEMM k=400) + relu ----------------
  if (u < 480) {
    const int o = u % 120, bg = u / 120;
    const int b = bg * 256 + tid;
    float* wL = smem;
    for (int t = tid; t < 400; t += 256) wL[t] = w3[(size_t)o * 400 + t];
    __syncthreads();
    float a0 = 0.f, a1 = 0.f, a2 = 0.f, a3 = 0.f;
#pragma unroll 8
    for (int k = 0; k < 400; k += 4) {
      a0 = fmaf(h2[(size_t)(k + 0) * NB + b], wL[k + 0], a0);
      a1 = fmaf(h2[(size_t)(k + 1) * NB + b], wL[k + 1], a1);
      a2 = fmaf(h2[(size_t)(k + 2) * NB + b], wL[k + 2], a2);
      a3 = fmaf(h2[(size_t)(k + 3) * NB + b], wL[k + 3], a3);
    }
    h3[(size_t)o * NB + b] = fmaxf((a0 + a1) + (a2 + a3) + b3[o], 0.f);
  }
  gbar(bar + 3);

  // ---------------- P4: fc2 + relu ----------------
  if (u < 336) {
    const int bg = u % 16, jg = u / 16;       // 21 jgroups
    const int b = bg * 64 + (tid & 63);
    const int jj = tid >> 6;                  // wave-uniform 0..3
    const int j = jg * 4 + jj;
    float* wL = smem;                         // 480 f
    for (int t = tid; t < 480; t += 256) wL[t] = fc2w[(size_t)jg * 480 + t];
    __syncthreads();
    const float* wp = &wL[jj * 120];
    float a0 = 0.f, a1 = 0.f;
#pragma unroll
    for (int k = 0; k < 120; k += 2) {
      a0 = fmaf(h3[(size_t)(k + 0) * NB + b], wp[k + 0], a0);
      a1 = fmaf(h3[(size_t)(k + 1) * NB + b], wp[k + 1], a1);
    }
    h4[(size_t)j * NB + b] = fmaxf(a0 + a1 + fc2b[j], 0.f);
  }
  gbar(bar + 4);

  // ---------------- P5: fc3 ----------------
  if (u < 48) {
    const int bg = u % 16, ig = u / 16;       // 3 igroups
    const int b = bg * 64 + (tid & 63);
    const int ii = tid >> 6;                  // wave-uniform 0..3
    const int i = ig * 4 + ii;
    float* wL = smem;                         // 336 f
    for (int t = tid; t < 336; t += 256) {
      const int gi = ig * 336 + t;
      wL[t] = (gi < 840) ? fc3w[gi] : 0.f;
    }
    __syncthreads();
    if (i < 10) {
      const float* wp = &wL[ii * 84];
      float a0 = 0.f, a1 = 0.f;
#pragma unroll
      for (int jx = 0; jx < 84; jx += 2) {
        a0 = fmaf(h4[(size_t)(jx + 0) * NB + b], wp[jx + 0], a0);
        a1 = fmaf(h4[(size_t)(jx + 1) * NB + b], wp[jx + 1], a1);
      }
      out[(size_t)b * 10 + i] = a0 + a1 + fc3b[i];
    }
  }
}

// ---------------------------------------------------------------------------
extern "C" void kernel_launch(void* const* d_in, const int* in_sizes, int n_in,
                              void* d_out, int out_size, void* d_ws, size_t ws_size,
                              hipStream_t stream) {
  const float* x    = (const float*)d_in[0];
  const float* w1   = (const float*)d_in[1];
  const float* b1   = (const float*)d_in[2];
  const float* w2   = (const float*)d_in[3];
  const float* b2   = (const float*)d_in[4];
  const float* w3   = (const float*)d_in[5];
  const float* b3   = (const float*)d_in[6];
  const float* fc2w = (const float*)d_in[7];
  const float* fc2b = (const float*)d_in[8];
  const float* fc3w = (const float*)d_in[9];
  const float* fc3b = (const float*)d_in[10];
  float* out = (float*)d_out;

  float* ws = (float*)d_ws;
  float* xT = ws;                         // 3*32*32*1024  = 3,145,728 f
  float* h1 = xT + 3145728;               // 6*14*14*1024  = 1,204,224 f
  float* h2 = h1 + 1204224;               // 16*5*5*1024   =   409,600 f
  float* h3 = h2 + 409600;                // 120*1024      =   122,880 f
  float* h4 = h3 + 122880;                // 84*1024       =    86,016 f  (~19.9 MB total)
  unsigned* bar = (unsigned*)((char*)d_ws + (size_t)(32 << 20));  // 32 MB offset, clear of data

  k_zero<<<1, 64, 0, stream>>>(bar);
  k_all<<<dim3(NBLK), 256, 0, stream>>>(x, w1, b1, w2, b2, w3, b3,
                                        fc2w, fc2b, fc3w, fc3b, out,
                                        xT, h1, h2, h3, h4, bar);
}

// Round 5
// 175.942 us; speedup vs baseline: 4.6010x; 4.6010x over previous
//
#include <hip/hip_runtime.h>
#include <math.h>

#define NB 1024  // batch

// ---------------------------------------------------------------------------
// K1: untied conv1 + bias + relu + 2x2 maxpool, reading x DIRECTLY (no
//     transpose kernel). x: (B,3,32,32); lane=batch -> per-lane stride 3072
//     floats; each window row (6 floats, w-offset even) = 3 aligned float2
//     loads, 54 load instrs/thread, all independent (deep ILP).
//     w1: (6,3,28,28,25)  b1: (6,28,28)  h1: (6,14,14,B)
// ---------------------------------------------------------------------------
__global__ __launch_bounds__(256) void k_conv1(const float* __restrict__ x,
                                               const float* __restrict__ w1,
                                               const float* __restrict__ b1,
                                               float* __restrict__ h1) {
  const int pos = blockIdx.x;            // 0..195
  const int ph = pos / 14, pw = pos % 14;
  const int b = blockIdx.y * 256 + threadIdx.x;

  // weights staged in LDS: chunk = o*12 + c*4 + i*2 + j (72 chunks, pad 25->28)
  __shared__ __align__(16) float wL[72 * 28];
  __shared__ float bL[24];
  for (int t = threadIdx.x; t < 72 * 25; t += 256) {
    const int chunk = t / 25, p = t - chunk * 25;
    const int o = chunk / 12, rem = chunk - o * 12;
    const int c = rem >> 2, i = (rem >> 1) & 1, j = rem & 1;
    wL[chunk * 28 + p] =
        w1[((size_t)((o * 3 + c) * 28 + (2 * ph + i)) * 28 + (2 * pw + j)) * 25 + p];
  }
  if (threadIdx.x < 24) {
    const int o = threadIdx.x >> 2, i = (threadIdx.x >> 1) & 1, j = threadIdx.x & 1;
    bL[threadIdx.x] = b1[(size_t)(o * 28 + (2 * ph + i)) * 28 + (2 * pw + j)];
  }
  __syncthreads();

  float acc[6][2][2];
#pragma unroll
  for (int o = 0; o < 6; ++o)
#pragma unroll
    for (int i = 0; i < 2; ++i)
#pragma unroll
      for (int j = 0; j < 2; ++j) acc[o][i][j] = 0.f;

  for (int c = 0; c < 3; ++c) {
    float xw[6][6];
#pragma unroll
    for (int dh = 0; dh < 6; ++dh) {
      // base = x[b][c][2ph+dh][2pw]; 2pw even -> 8B-aligned float2 x3
      const float* row = x + (size_t)b * 3072 + c * 1024 + (2 * ph + dh) * 32 + 2 * pw;
      const float2 r0 = *reinterpret_cast<const float2*>(row + 0);
      const float2 r1 = *reinterpret_cast<const float2*>(row + 2);
      const float2 r2 = *reinterpret_cast<const float2*>(row + 4);
      xw[dh][0] = r0.x; xw[dh][1] = r0.y;
      xw[dh][2] = r1.x; xw[dh][3] = r1.y;
      xw[dh][4] = r2.x; xw[dh][5] = r2.y;
    }
#pragma unroll
    for (int o = 0; o < 6; ++o)
#pragma unroll
      for (int i = 0; i < 2; ++i)
#pragma unroll
        for (int j = 0; j < 2; ++j) {
          const float* wp = &wL[((o * 3 + c) * 4 + i * 2 + j) * 28];
#pragma unroll
          for (int p = 0; p < 25; ++p)
            acc[o][i][j] = fmaf(xw[i + p / 5][j + p % 5], wp[p], acc[o][i][j]);
        }
  }

#pragma unroll
  for (int o = 0; o < 6; ++o) {
    float v[2][2];
#pragma unroll
    for (int i = 0; i < 2; ++i)
#pragma unroll
      for (int j = 0; j < 2; ++j)
        v[i][j] = fmaxf(acc[o][i][j] + bL[o * 4 + i * 2 + j], 0.f);
    const float m = fmaxf(fmaxf(v[0][0], v[0][1]), fmaxf(v[1][0], v[1][1]));
    h1[((size_t)(o * 14 + ph) * 14 + pw) * NB + b] = m;
  }
}

// ---------------------------------------------------------------------------
// K2: untied conv2 + bias + relu + 2x2 maxpool
//     h1: (6,14,14,B)  w2: (16,6,10,10,25)  b2: (16,10,10)  h2: (16,5,5,B)
//     o-split = 2 per block -> grid (25,8,4) = 800 blocks (3.1/CU, 2x R2's
//     occupancy, half the per-thread latency chain).
// ---------------------------------------------------------------------------
__global__ __launch_bounds__(256) void k_conv2(const float* __restrict__ h1,
                                               const float* __restrict__ w2,
                                               const float* __restrict__ b2,
                                               float* __restrict__ h2) {
  const int pos = blockIdx.x;            // 0..24
  const int ph = pos / 5, pw = pos % 5;
  const int og = blockIdx.y;             // 0..7 (2 o's each)
  const int b = blockIdx.z * 256 + threadIdx.x;

  // chunk = oo*24 + c*4 + i*2 + j  (48 chunks of 25, padded to 28)
  __shared__ __align__(16) float wL[48 * 28];
  __shared__ float bL[8];
  for (int t = threadIdx.x; t < 48 * 25; t += 256) {
    const int chunk = t / 25, p = t - chunk * 25;
    const int oo = chunk / 24, rem = chunk - oo * 24;
    const int c = rem >> 2, i = (rem >> 1) & 1, j = rem & 1;
    const int o = og * 2 + oo;
    wL[chunk * 28 + p] =
        w2[((size_t)((o * 6 + c) * 10 + (2 * ph + i)) * 10 + (2 * pw + j)) * 25 + p];
  }
  if (threadIdx.x < 8) {
    const int oo = threadIdx.x >> 2, i = (threadIdx.x >> 1) & 1, j = threadIdx.x & 1;
    const int o = og * 2 + oo;
    bL[threadIdx.x] = b2[(size_t)(o * 10 + (2 * ph + i)) * 10 + (2 * pw + j)];
  }
  __syncthreads();

  float acc[2][2][2];
#pragma unroll
  for (int oo = 0; oo < 2; ++oo)
#pragma unroll
    for (int i = 0; i < 2; ++i)
#pragma unroll
      for (int j = 0; j < 2; ++j) acc[oo][i][j] = 0.f;

  for (int c = 0; c < 6; ++c) {
    float xw[6][6];
#pragma unroll
    for (int dh = 0; dh < 6; ++dh)
#pragma unroll
      for (int dw = 0; dw < 6; ++dw)
        xw[dh][dw] =
            h1[((size_t)(c * 14 + (2 * ph + dh)) * 14 + (2 * pw + dw)) * NB + b];
#pragma unroll
    for (int oo = 0; oo < 2; ++oo)
#pragma unroll
      for (int i = 0; i < 2; ++i)
#pragma unroll
        for (int j = 0; j < 2; ++j) {
          const float* wp = &wL[((oo * 6 + c) * 4 + i * 2 + j) * 28];
#pragma unroll
          for (int p = 0; p < 25; ++p)
            acc[oo][i][j] = fmaf(xw[i + p / 5][j + p % 5], wp[p], acc[oo][i][j]);
        }
  }

#pragma unroll
  for (int oo = 0; oo < 2; ++oo) {
    const int o = og * 2 + oo;
    float v[2][2];
#pragma unroll
    for (int i = 0; i < 2; ++i)
#pragma unroll
      for (int j = 0; j < 2; ++j)
        v[i][j] = fmaxf(acc[oo][i][j] + bL[oo * 4 + i * 2 + j], 0.f);
    const float m = fmaxf(fmaxf(v[0][0], v[0][1]), fmaxf(v[1][0], v[1][1]));
    h2[((size_t)(o * 5 + ph) * 5 + pw) * NB + b] = m;
  }
}

// ---------------------------------------------------------------------------
// K3: conv3 == GEMM: h3[o,b] = relu( sum_k w3[o,k] * h2[k,b] + b3[o] ), k=400
// ---------------------------------------------------------------------------
__global__ __launch_bounds__(256) void k_conv3(const float* __restrict__ h2,
                                               const float* __restrict__ w3,
                                               const float* __restrict__ b3,
                                               float* __restrict__ h3) {
  const int o = blockIdx.x;              // 0..119
  const int b = blockIdx.y * 256 + threadIdx.x;
  __shared__ __align__(16) float wL[400];
  for (int t = threadIdx.x; t < 400; t += 256) wL[t] = w3[(size_t)o * 400 + t];
  __syncthreads();

  float a0 = 0.f, a1 = 0.f, a2 = 0.f, a3 = 0.f;
#pragma unroll 8
  for (int k = 0; k < 400; k += 4) {
    a0 = fmaf(h2[(size_t)(k + 0) * NB + b], wL[k + 0], a0);
    a1 = fmaf(h2[(size_t)(k + 1) * NB + b], wL[k + 1], a1);
    a2 = fmaf(h2[(size_t)(k + 2) * NB + b], wL[k + 2], a2);
    a3 = fmaf(h2[(size_t)(k + 3) * NB + b], wL[k + 3], a3);
  }
  h3[(size_t)o * NB + b] = fmaxf((a0 + a1) + (a2 + a3) + b3[o], 0.f);
}

// ---------------------------------------------------------------------------
// K4a: h4[j,b] = relu( dot(h3[:,b], fc2w[j,:]) + fc2b[j] ), j<84
// ---------------------------------------------------------------------------
__global__ __launch_bounds__(256) void k_fc2(const float* __restrict__ h3,
                                             const float* __restrict__ fc2w,
                                             const float* __restrict__ fc2b,
                                             float* __restrict__ h4) {
  const int b = blockIdx.x * 64 + (threadIdx.x & 63);
  const int jj = threadIdx.x >> 6;                    // wave-uniform 0..3
  const int j = blockIdx.y * 4 + jj;
  __shared__ __align__(16) float wL[4 * 120];
  for (int t = threadIdx.x; t < 480; t += 256)
    wL[t] = fc2w[(size_t)blockIdx.y * 480 + t];
  __syncthreads();

  const float* __restrict__ wp = &wL[jj * 120];
  float a0 = 0.f, a1 = 0.f;
#pragma unroll
  for (int k = 0; k < 120; k += 2) {
    a0 = fmaf(h3[(size_t)(k + 0) * NB + b], wp[k + 0], a0);
    a1 = fmaf(h3[(size_t)(k + 1) * NB + b], wp[k + 1], a1);
  }
  h4[(size_t)j * NB + b] = fmaxf(a0 + a1 + fc2b[j], 0.f);
}

// ---------------------------------------------------------------------------
// K4b: out[b,i] = dot(h4[:,b], fc3w[i,:]) + fc3b[i], i<10
// ---------------------------------------------------------------------------
__global__ __launch_bounds__(256) void k_fc3(const float* __restrict__ h4,
                                             const float* __restrict__ fc3w,
                                             const float* __restrict__ fc3b,
                                             float* __restrict__ out) {
  const int b = blockIdx.x * 64 + (threadIdx.x & 63);
  const int ii = threadIdx.x >> 6;                    // wave-uniform 0..3
  const int i = blockIdx.y * 4 + ii;
  __shared__ __align__(16) float wL[4 * 84];
  for (int t = threadIdx.x; t < 336; t += 256) {
    const int gi = blockIdx.y * 336 + t;
    wL[t] = (gi < 840) ? fc3w[gi] : 0.f;
  }
  __syncthreads();

  if (i < 10) {
    const float* __restrict__ wp = &wL[ii * 84];
    float a0 = 0.f, a1 = 0.f;
#pragma unroll
    for (int j = 0; j < 84; j += 2) {
      a0 = fmaf(h4[(size_t)(j + 0) * NB + b], wp[j + 0], a0);
      a1 = fmaf(h4[(size_t)(j + 1) * NB + b], wp[j + 1], a1);
    }
    out[(size_t)b * 10 + i] = a0 + a1 + fc3b[i];
  }
}

// ---------------------------------------------------------------------------
extern "C" void kernel_launch(void* const* d_in, const int* in_sizes, int n_in,
                              void* d_out, int out_size, void* d_ws, size_t ws_size,
                              hipStream_t stream) {
  const float* x    = (const float*)d_in[0];
  const float* w1   = (const float*)d_in[1];
  const float* b1   = (const float*)d_in[2];
  const float* w2   = (const float*)d_in[3];
  const float* b2   = (const float*)d_in[4];
  const float* w3   = (const float*)d_in[5];
  const float* b3   = (const float*)d_in[6];
  const float* fc2w = (const float*)d_in[7];
  const float* fc2b = (const float*)d_in[8];
  const float* fc3w = (const float*)d_in[9];
  const float* fc3b = (const float*)d_in[10];
  float* out = (float*)d_out;

  float* ws = (float*)d_ws;
  float* h1 = ws;                         // 6*14*14*1024  = 1,204,224 f
  float* h2 = h1 + 1204224;               // 16*5*5*1024   =   409,600 f
  float* h3 = h2 + 409600;                // 120*1024      =   122,880 f
  float* h4 = h3 + 122880;                // 84*1024       =    86,016 f (~7.3 MB)

  k_conv1<<<dim3(196, 4), 256, 0, stream>>>(x, w1, b1, h1);
  k_conv2<<<dim3(25, 8, 4), 256, 0, stream>>>(h1, w2, b2, h2);
  k_conv3<<<dim3(120, 4), 256, 0, stream>>>(h2, w3, b3, h3);
  k_fc2<<<dim3(16, 21), 256, 0, stream>>>(h3, fc2w, fc2b, h4);
  k_fc3<<<dim3(16, 3), 256, 0, stream>>>(h4, fc3w, fc3b, out);
}

// Round 6
// 168.255 us; speedup vs baseline: 4.8112x; 1.0457x over previous
//
#include <hip/hip_runtime.h>
#include <math.h>

#define NB 1024  // batch

// ---------------------------------------------------------------------------
// K0: transpose x (B, C*H*W=3072) -> xT (3072, B), 64x64 LDS tiles
// ---------------------------------------------------------------------------
__global__ __launch_bounds__(256) void k_transpose(const float* __restrict__ x,
                                                   float* __restrict__ xT) {
  __shared__ float tile[64][65];
  const int c0 = blockIdx.x * 64;   // chw tile
  const int b0 = blockIdx.y * 64;   // batch tile
  const int tx = threadIdx.x & 63;
  const int ty = threadIdx.x >> 6;
#pragma unroll
  for (int r = 0; r < 16; ++r) {
    const int bb = r * 4 + ty;
    tile[bb][tx] = x[(size_t)(b0 + bb) * 3072 + c0 + tx];  // coalesced over chw
  }
  __syncthreads();
#pragma unroll
  for (int r = 0; r < 16; ++r) {
    const int cc = r * 4 + ty;
    xT[(size_t)(c0 + cc) * NB + b0 + tx] = tile[tx][cc];   // coalesced over b
  }
}

// ---------------------------------------------------------------------------
// K1: untied conv1 + bias + relu + 2x2 maxpool, reading xT (3,32,32,B).
//     1D grid 784, XCD-swizzled: xcd=w&7 -> (bg = xcd>>1, poshalf = xcd&1),
//     pos = poshalf*98 + w>>3. Same-XCD blocks share one 256-batch group and
//     a contiguous ph range -> per-XCD xT working set ~1.8 MB < 4 MB L2.
//     w1: (6,3,28,28,25)  b1: (6,28,28)  h1: (6,14,14,B)
// ---------------------------------------------------------------------------
__global__ __launch_bounds__(256) void k_conv1(const float* __restrict__ xT,
                                               const float* __restrict__ w1,
                                               const float* __restrict__ b1,
                                               float* __restrict__ h1) {
  const int w = blockIdx.x;              // 0..783
  const int xcd = w & 7, k = w >> 3;     // k: 0..97
  const int bg = xcd >> 1;               // 0..3
  const int pos = (xcd & 1) * 98 + k;    // 0..195
  const int ph = pos / 14, pw = pos % 14;
  const int b = bg * 256 + threadIdx.x;

  // weights staged in LDS: chunk = o*12 + c*4 + i*2 + j (72 chunks, pad 25->28)
  __shared__ __align__(16) float wL[72 * 28];
  __shared__ float bL[24];
  for (int t = threadIdx.x; t < 72 * 25; t += 256) {
    const int chunk = t / 25, p = t - chunk * 25;
    const int o = chunk / 12, rem = chunk - o * 12;
    const int c = rem >> 2, i = (rem >> 1) & 1, j = rem & 1;
    wL[chunk * 28 + p] =
        w1[((size_t)((o * 3 + c) * 28 + (2 * ph + i)) * 28 + (2 * pw + j)) * 25 + p];
  }
  if (threadIdx.x < 24) {
    const int o = threadIdx.x >> 2, i = (threadIdx.x >> 1) & 1, j = threadIdx.x & 1;
    bL[threadIdx.x] = b1[(size_t)(o * 28 + (2 * ph + i)) * 28 + (2 * pw + j)];
  }
  __syncthreads();

  float acc[6][2][2];
#pragma unroll
  for (int o = 0; o < 6; ++o)
#pragma unroll
    for (int i = 0; i < 2; ++i)
#pragma unroll
      for (int j = 0; j < 2; ++j) acc[o][i][j] = 0.f;

  for (int c = 0; c < 3; ++c) {
    float xw[6][6];
#pragma unroll
    for (int dh = 0; dh < 6; ++dh)
#pragma unroll
      for (int dw = 0; dw < 6; ++dw)
        xw[dh][dw] =
            xT[((size_t)(c * 32 + (2 * ph + dh)) * 32 + (2 * pw + dw)) * NB + b];
#pragma unroll
    for (int o = 0; o < 6; ++o)
#pragma unroll
      for (int i = 0; i < 2; ++i)
#pragma unroll
        for (int j = 0; j < 2; ++j) {
          const float* wp = &wL[((o * 3 + c) * 4 + i * 2 + j) * 28];
#pragma unroll
          for (int p = 0; p < 25; ++p)
            acc[o][i][j] = fmaf(xw[i + p / 5][j + p % 5], wp[p], acc[o][i][j]);
        }
  }

#pragma unroll
  for (int o = 0; o < 6; ++o) {
    float v[2][2];
#pragma unroll
    for (int i = 0; i < 2; ++i)
#pragma unroll
      for (int j = 0; j < 2; ++j)
        v[i][j] = fmaxf(acc[o][i][j] + bL[o * 4 + i * 2 + j], 0.f);
    const float m = fmaxf(fmaxf(v[0][0], v[0][1]), fmaxf(v[1][0], v[1][1]));
    h1[((size_t)(o * 14 + ph) * 14 + pw) * NB + b] = m;
  }
}

// ---------------------------------------------------------------------------
// K2: untied conv2 + bias + relu + 2x2 maxpool
//     1D grid 800, XCD-swizzled: xcd=w&7 -> bg=xcd>>1; unit=(xcd&1)*100+w>>3
//     -> og=unit/25, pos=unit%25. Per-XCD h1 working set = one bg slice
//     (1.2 MB) and all og-blocks of a bg share the same input windows.
//     h1: (6,14,14,B)  w2: (16,6,10,10,25)  b2: (16,10,10)  h2: (16,5,5,B)
// ---------------------------------------------------------------------------
__global__ __launch_bounds__(256) void k_conv2(const float* __restrict__ h1,
                                               const float* __restrict__ w2,
                                               const float* __restrict__ b2,
                                               float* __restrict__ h2) {
  const int w = blockIdx.x;              // 0..799
  const int xcd = w & 7, k = w >> 3;     // k: 0..99
  const int bg = xcd >> 1;               // 0..3
  const int unit = (xcd & 1) * 100 + k;  // 0..199
  const int og = unit / 25;              // 0..7 (2 o's each)
  const int pos = unit % 25;
  const int ph = pos / 5, pw = pos % 5;
  const int b = bg * 256 + threadIdx.x;

  // chunk = oo*24 + c*4 + i*2 + j  (48 chunks of 25, padded to 28)
  __shared__ __align__(16) float wL[48 * 28];
  __shared__ float bL[8];
  for (int t = threadIdx.x; t < 48 * 25; t += 256) {
    const int chunk = t / 25, p = t - chunk * 25;
    const int oo = chunk / 24, rem = chunk - oo * 24;
    const int c = rem >> 2, i = (rem >> 1) & 1, j = rem & 1;
    const int o = og * 2 + oo;
    wL[chunk * 28 + p] =
        w2[((size_t)((o * 6 + c) * 10 + (2 * ph + i)) * 10 + (2 * pw + j)) * 25 + p];
  }
  if (threadIdx.x < 8) {
    const int oo = threadIdx.x >> 2, i = (threadIdx.x >> 1) & 1, j = threadIdx.x & 1;
    const int o = og * 2 + oo;
    bL[threadIdx.x] = b2[(size_t)(o * 10 + (2 * ph + i)) * 10 + (2 * pw + j)];
  }
  __syncthreads();

  float acc[2][2][2];
#pragma unroll
  for (int oo = 0; oo < 2; ++oo)
#pragma unroll
    for (int i = 0; i < 2; ++i)
#pragma unroll
      for (int j = 0; j < 2; ++j) acc[oo][i][j] = 0.f;

  for (int c = 0; c < 6; ++c) {
    float xw[6][6];
#pragma unroll
    for (int dh = 0; dh < 6; ++dh)
#pragma unroll
      for (int dw = 0; dw < 6; ++dw)
        xw[dh][dw] =
            h1[((size_t)(c * 14 + (2 * ph + dh)) * 14 + (2 * pw + dw)) * NB + b];
#pragma unroll
    for (int oo = 0; oo < 2; ++oo)
#pragma unroll
      for (int i = 0; i < 2; ++i)
#pragma unroll
        for (int j = 0; j < 2; ++j) {
          const float* wp = &wL[((oo * 6 + c) * 4 + i * 2 + j) * 28];
#pragma unroll
          for (int p = 0; p < 25; ++p)
            acc[oo][i][j] = fmaf(xw[i + p / 5][j + p % 5], wp[p], acc[oo][i][j]);
        }
  }

#pragma unroll
  for (int oo = 0; oo < 2; ++oo) {
    const int o = og * 2 + oo;
    float v[2][2];
#pragma unroll
    for (int i = 0; i < 2; ++i)
#pragma unroll
      for (int j = 0; j < 2; ++j)
        v[i][j] = fmaxf(acc[oo][i][j] + bL[oo * 4 + i * 2 + j], 0.f);
    const float m = fmaxf(fmaxf(v[0][0], v[0][1]), fmaxf(v[1][0], v[1][1]));
    h2[((size_t)(o * 5 + ph) * 5 + pw) * NB + b] = m;
  }
}

// ---------------------------------------------------------------------------
// K3: conv3 == GEMM: h3[o,b] = relu( sum_k w3[o,k] * h2[k,b] + b3[o] ), k=400
//     1D grid 480, XCD-swizzled: bg = (w&7)>>1, o = ((w&1))*60 + (w>>3).
// ---------------------------------------------------------------------------
__global__ __launch_bounds__(256) void k_conv3(const float* __restrict__ h2,
                                               const float* __restrict__ w3,
                                               const float* __restrict__ b3,
                                               float* __restrict__ h3) {
  const int w = blockIdx.x;              // 0..479
  const int xcd = w & 7, k2 = w >> 3;    // k2: 0..59
  const int bg = xcd >> 1;               // 0..3
  const int o = (xcd & 1) * 60 + k2;     // 0..119
  const int b = bg * 256 + threadIdx.x;
  __shared__ __align__(16) float wL[400];
  for (int t = threadIdx.x; t < 400; t += 256) wL[t] = w3[(size_t)o * 400 + t];
  __syncthreads();

  float a0 = 0.f, a1 = 0.f, a2 = 0.f, a3 = 0.f;
#pragma unroll 8
  for (int k = 0; k < 400; k += 4) {
    a0 = fmaf(h2[(size_t)(k + 0) * NB + b], wL[k + 0], a0);
    a1 = fmaf(h2[(size_t)(k + 1) * NB + b], wL[k + 1], a1);
    a2 = fmaf(h2[(size_t)(k + 2) * NB + b], wL[k + 2], a2);
    a3 = fmaf(h2[(size_t)(k + 3) * NB + b], wL[k + 3], a3);
  }
  h3[(size_t)o * NB + b] = fmaxf((a0 + a1) + (a2 + a3) + b3[o], 0.f);
}

// ---------------------------------------------------------------------------
// K4: fused FC tail. Block = 16 batches (grid 64). Stage h3[120][16] in LDS,
//     fc2+relu into h4L[84][16], then fc3 -> out. Per-batch locality only.
// ---------------------------------------------------------------------------
__global__ __launch_bounds__(256) void k_fctail(const float* __restrict__ h3,
                                                const float* __restrict__ fc2w,
                                                const float* __restrict__ fc2b,
                                                const float* __restrict__ fc3w,
                                                const float* __restrict__ fc3b,
                                                float* __restrict__ out) {
  const int b0 = blockIdx.x * 16;
  const int tid = threadIdx.x;
  __shared__ float h3L[120 * 16];
  __shared__ float h4L[84 * 16];

  for (int t = tid; t < 120 * 16; t += 256) {
    const int k = t >> 4, bb = t & 15;
    h3L[t] = h3[(size_t)k * NB + b0 + bb];
  }
  __syncthreads();

  const int bb = tid & 15;
  {
    const int jbase = tid >> 4;          // 0..15
#pragma unroll
    for (int jr = 0; jr < 6; ++jr) {     // 16*6 = 96 >= 84
      const int j = jbase + jr * 16;
      if (j < 84) {
        const float* __restrict__ wp = fc2w + (size_t)j * 120;
        float a0 = 0.f, a1 = 0.f;
#pragma unroll
        for (int k = 0; k < 120; k += 2) {
          a0 = fmaf(h3L[(k + 0) * 16 + bb], wp[k + 0], a0);
          a1 = fmaf(h3L[(k + 1) * 16 + bb], wp[k + 1], a1);
        }
        h4L[j * 16 + bb] = fmaxf(a0 + a1 + fc2b[j], 0.f);
      }
    }
  }
  __syncthreads();

  if (tid < 160) {
    const int i = tid >> 4;              // 0..9
    const float* __restrict__ wp = fc3w + (size_t)i * 84;
    float a0 = 0.f, a1 = 0.f;
#pragma unroll
    for (int j = 0; j < 84; j += 2) {
      a0 = fmaf(h4L[(j + 0) * 16 + bb], wp[j + 0], a0);
      a1 = fmaf(h4L[(j + 1) * 16 + bb], wp[j + 1], a1);
    }
    out[(size_t)(b0 + bb) * 10 + i] = a0 + a1 + fc3b[i];
  }
}

// ---------------------------------------------------------------------------
extern "C" void kernel_launch(void* const* d_in, const int* in_sizes, int n_in,
                              void* d_out, int out_size, void* d_ws, size_t ws_size,
                              hipStream_t stream) {
  const float* x    = (const float*)d_in[0];
  const float* w1   = (const float*)d_in[1];
  const float* b1   = (const float*)d_in[2];
  const float* w2   = (const float*)d_in[3];
  const float* b2   = (const float*)d_in[4];
  const float* w3   = (const float*)d_in[5];
  const float* b3   = (const float*)d_in[6];
  const float* fc2w = (const float*)d_in[7];
  const float* fc2b = (const float*)d_in[8];
  const float* fc3w = (const float*)d_in[9];
  const float* fc3b = (const float*)d_in[10];
  float* out = (float*)d_out;

  float* ws = (float*)d_ws;
  float* xT = ws;                         // 3*32*32*1024  = 3,145,728 f
  float* h1 = xT + 3145728;               // 6*14*14*1024  = 1,204,224 f
  float* h2 = h1 + 1204224;               // 16*5*5*1024   =   409,600 f
  float* h3 = h2 + 409600;                // 120*1024      =   122,880 f  (~19 MB)

  k_transpose<<<dim3(48, 16), 256, 0, stream>>>(x, xT);
  k_conv1<<<dim3(784), 256, 0, stream>>>(xT, w1, b1, h1);
  k_conv2<<<dim3(800), 256, 0, stream>>>(h1, w2, b2, h2);
  k_conv3<<<dim3(480), 256, 0, stream>>>(h2, w3, b3, h3);
  k_fctail<<<dim3(64), 256, 0, stream>>>(h3, fc2w, fc2b, fc3w, fc3b, out);
}

// Round 8
// 165.958 us; speedup vs baseline: 4.8778x; 1.0138x over previous
//
#include <hip/hip_runtime.h>
#include <math.h>

#define NB 1024  // batch

// ---------------------------------------------------------------------------
// K0: transpose x (B, C*H*W=3072) -> xT (3072, B), 64x64 LDS tiles
// ---------------------------------------------------------------------------
__global__ __launch_bounds__(256) void k_transpose(const float* __restrict__ x,
                                                   float* __restrict__ xT) {
  __shared__ float tile[64][65];
  const int c0 = blockIdx.x * 64;   // chw tile
  const int b0 = blockIdx.y * 64;   // batch tile
  const int tx = threadIdx.x & 63;
  const int ty = threadIdx.x >> 6;
#pragma unroll
  for (int r = 0; r < 16; ++r) {
    const int bb = r * 4 + ty;
    tile[bb][tx] = x[(size_t)(b0 + bb) * 3072 + c0 + tx];  // coalesced over chw
  }
  __syncthreads();
#pragma unroll
  for (int r = 0; r < 16; ++r) {
    const int cc = r * 4 + ty;
    xT[(size_t)(c0 + cc) * NB + b0 + tx] = tile[tx][cc];   // coalesced over b
  }
}

// ---------------------------------------------------------------------------
// K1: untied conv1 + bias + relu + 2x2 maxpool. xT (3,32,32,B) -> h1 (6,14,14,B)
//     128 threads, 2 batches/thread (float2): each LDS weight read feeds 2
//     FMAs, global loads are b64 — instruction count halved vs R6.
//     Grid 784, XCD-swizzled (same mapping as R6).
// ---------------------------------------------------------------------------
__global__ __launch_bounds__(128) void k_conv1(const float* __restrict__ xT,
                                               const float* __restrict__ w1,
                                               const float* __restrict__ b1,
                                               float* __restrict__ h1) {
  const int w = blockIdx.x;              // 0..783
  const int xcd = w & 7, kk = w >> 3;    // kk: 0..97
  const int bg = xcd >> 1;               // 0..3
  const int pos = (xcd & 1) * 98 + kk;   // 0..195
  const int ph = pos / 14, pw = pos % 14;
  const int b = bg * 256 + threadIdx.x * 2;

  // weights staged in LDS: chunk = o*12 + c*4 + i*2 + j (72 chunks, pad 25->28)
  __shared__ __align__(16) float wL[72 * 28];
  __shared__ float bL[24];
  for (int t = threadIdx.x; t < 72 * 25; t += 128) {
    const int chunk = t / 25, p = t - chunk * 25;
    const int o = chunk / 12, rem = chunk - o * 12;
    const int c = rem >> 2, i = (rem >> 1) & 1, j = rem & 1;
    wL[chunk * 28 + p] =
        w1[((size_t)((o * 3 + c) * 28 + (2 * ph + i)) * 28 + (2 * pw + j)) * 25 + p];
  }
  if (threadIdx.x < 24) {
    const int o = threadIdx.x >> 2, i = (threadIdx.x >> 1) & 1, j = threadIdx.x & 1;
    bL[threadIdx.x] = b1[(size_t)(o * 28 + (2 * ph + i)) * 28 + (2 * pw + j)];
  }
  __syncthreads();

  float2 acc[6][2][2];
#pragma unroll
  for (int o = 0; o < 6; ++o)
#pragma unroll
    for (int i = 0; i < 2; ++i)
#pragma unroll
      for (int j = 0; j < 2; ++j) { acc[o][i][j].x = 0.f; acc[o][i][j].y = 0.f; }

  for (int c = 0; c < 3; ++c) {
    float2 xw[6][6];
#pragma unroll
    for (int dh = 0; dh < 6; ++dh)
#pragma unroll
      for (int dw = 0; dw < 6; ++dw)
        xw[dh][dw] = *reinterpret_cast<const float2*>(
            &xT[((size_t)(c * 32 + (2 * ph + dh)) * 32 + (2 * pw + dw)) * NB + b]);
#pragma unroll
    for (int o = 0; o < 6; ++o)
#pragma unroll
      for (int i = 0; i < 2; ++i)
#pragma unroll
        for (int j = 0; j < 2; ++j) {
          const float* wp = &wL[((o * 3 + c) * 4 + i * 2 + j) * 28];
#pragma unroll
          for (int p = 0; p < 25; ++p) {
            const float wv = wp[p];
            const float2 xv = xw[i + p / 5][j + p % 5];
            acc[o][i][j].x = fmaf(xv.x, wv, acc[o][i][j].x);
            acc[o][i][j].y = fmaf(xv.y, wv, acc[o][i][j].y);
          }
        }
  }

#pragma unroll
  for (int o = 0; o < 6; ++o) {
    float2 v[2][2];
#pragma unroll
    for (int i = 0; i < 2; ++i)
#pragma unroll
      for (int j = 0; j < 2; ++j) {
        const float bias = bL[o * 4 + i * 2 + j];
        v[i][j].x = fmaxf(acc[o][i][j].x + bias, 0.f);
        v[i][j].y = fmaxf(acc[o][i][j].y + bias, 0.f);
      }
    float2 m;
    m.x = fmaxf(fmaxf(v[0][0].x, v[0][1].x), fmaxf(v[1][0].x, v[1][1].x));
    m.y = fmaxf(fmaxf(v[0][0].y, v[0][1].y), fmaxf(v[1][0].y, v[1][1].y));
    *reinterpret_cast<float2*>(&h1[((size_t)(o * 14 + ph) * 14 + pw) * NB + b]) = m;
  }
}

// ---------------------------------------------------------------------------
// K2: untied conv2 + bias + relu + 2x2 maxpool. h1 (6,14,14,B) -> h2 (16,5,5,B)
//     128 threads, 2 batches/thread. Grid 800, XCD-swizzled (R6 mapping).
// ---------------------------------------------------------------------------
__global__ __launch_bounds__(128) void k_conv2(const float* __restrict__ h1,
                                               const float* __restrict__ w2,
                                               const float* __restrict__ b2,
                                               float* __restrict__ h2) {
  const int w = blockIdx.x;              // 0..799
  const int xcd = w & 7, kk = w >> 3;    // kk: 0..99
  const int bg = xcd >> 1;               // 0..3
  const int unit = (xcd & 1) * 100 + kk; // 0..199
  const int og = unit / 25;              // 0..7 (2 o's each)
  const int pos = unit % 25;
  const int ph = pos / 5, pw = pos % 5;
  const int b = bg * 256 + threadIdx.x * 2;

  // chunk = oo*24 + c*4 + i*2 + j  (48 chunks of 25, padded to 28)
  __shared__ __align__(16) float wL[48 * 28];
  __shared__ float bL[8];
  for (int t = threadIdx.x; t < 48 * 25; t += 128) {
    const int chunk = t / 25, p = t - chunk * 25;
    const int oo = chunk / 24, rem = chunk - oo * 24;
    const int c = rem >> 2, i = (rem >> 1) & 1, j = rem & 1;
    const int o = og * 2 + oo;
    wL[chunk * 28 + p] =
        w2[((size_t)((o * 6 + c) * 10 + (2 * ph + i)) * 10 + (2 * pw + j)) * 25 + p];
  }
  if (threadIdx.x < 8) {
    const int oo = threadIdx.x >> 2, i = (threadIdx.x >> 1) & 1, j = threadIdx.x & 1;
    const int o = og * 2 + oo;
    bL[threadIdx.x] = b2[(size_t)(o * 10 + (2 * ph + i)) * 10 + (2 * pw + j)];
  }
  __syncthreads();

  float2 acc[2][2][2];
#pragma unroll
  for (int oo = 0; oo < 2; ++oo)
#pragma unroll
    for (int i = 0; i < 2; ++i)
#pragma unroll
      for (int j = 0; j < 2; ++j) { acc[oo][i][j].x = 0.f; acc[oo][i][j].y = 0.f; }

  for (int c = 0; c < 6; ++c) {
    float2 xw[6][6];
#pragma unroll
    for (int dh = 0; dh < 6; ++dh)
#pragma unroll
      for (int dw = 0; dw < 6; ++dw)
        xw[dh][dw] = *reinterpret_cast<const float2*>(
            &h1[((size_t)(c * 14 + (2 * ph + dh)) * 14 + (2 * pw + dw)) * NB + b]);
#pragma unroll
    for (int oo = 0; oo < 2; ++oo)
#pragma unroll
      for (int i = 0; i < 2; ++i)
#pragma unroll
        for (int j = 0; j < 2; ++j) {
          const float* wp = &wL[((oo * 6 + c) * 4 + i * 2 + j) * 28];
#pragma unroll
          for (int p = 0; p < 25; ++p) {
            const float wv = wp[p];
            const float2 xv = xw[i + p / 5][j + p % 5];
            acc[oo][i][j].x = fmaf(xv.x, wv, acc[oo][i][j].x);
            acc[oo][i][j].y = fmaf(xv.y, wv, acc[oo][i][j].y);
          }
        }
  }

#pragma unroll
  for (int oo = 0; oo < 2; ++oo) {
    const int o = og * 2 + oo;
    float2 v[2][2];
#pragma unroll
    for (int i = 0; i < 2; ++i)
#pragma unroll
      for (int j = 0; j < 2; ++j) {
        const float bias = bL[oo * 4 + i * 2 + j];
        v[i][j].x = fmaxf(acc[oo][i][j].x + bias, 0.f);
        v[i][j].y = fmaxf(acc[oo][i][j].y + bias, 0.f);
      }
    float2 m;
    m.x = fmaxf(fmaxf(v[0][0].x, v[0][1].x), fmaxf(v[1][0].x, v[1][1].x));
    m.y = fmaxf(fmaxf(v[0][0].y, v[0][1].y), fmaxf(v[1][0].y, v[1][1].y));
    *reinterpret_cast<float2*>(&h2[((size_t)(o * 5 + ph) * 5 + pw) * NB + b]) = m;
  }
}

// ---------------------------------------------------------------------------
// K3: conv3 == GEMM k=400. 2 o's per block (halves h2 L2 re-read traffic),
//     2 batches/thread, 128 threads. Grid 240, XCD-swizzled.
// ---------------------------------------------------------------------------
__global__ __launch_bounds__(128) void k_conv3(const float* __restrict__ h2,
                                               const float* __restrict__ w3,
                                               const float* __restrict__ b3,
                                               float* __restrict__ h3) {
  const int w = blockIdx.x;              // 0..239
  const int xcd = w & 7, k2 = w >> 3;    // k2: 0..29
  const int bg = xcd >> 1;               // 0..3
  const int o = ((xcd & 1) * 30 + k2) * 2;  // 0,2,..,118
  const int b = bg * 256 + threadIdx.x * 2;

  __shared__ __align__(16) float wL[2][400];
  for (int t = threadIdx.x; t < 800; t += 128) {
    const int oo = t / 400, p = t - oo * 400;
    wL[oo][p] = w3[(size_t)(o + oo) * 400 + p];
  }
  __syncthreads();

  float2 a00 = {0.f, 0.f}, a01 = {0.f, 0.f}, a10 = {0.f, 0.f}, a11 = {0.f, 0.f};
#pragma unroll 4
  for (int k = 0; k < 400; k += 2) {
    const float2 x0 = *reinterpret_cast<const float2*>(&h2[(size_t)(k + 0) * NB + b]);
    const float2 x1 = *reinterpret_cast<const float2*>(&h2[(size_t)(k + 1) * NB + b]);
    const float w00 = wL[0][k], w01 = wL[0][k + 1];
    const float w10 = wL[1][k], w11 = wL[1][k + 1];
    a00.x = fmaf(x0.x, w00, a00.x); a00.y = fmaf(x0.y, w00, a00.y);
    a01.x = fmaf(x1.x, w01, a01.x); a01.y = fmaf(x1.y, w01, a01.y);
    a10.x = fmaf(x0.x, w10, a10.x); a10.y = fmaf(x0.y, w10, a10.y);
    a11.x = fmaf(x1.x, w11, a11.x); a11.y = fmaf(x1.y, w11, a11.y);
  }
  float2 r0, r1;
  r0.x = fmaxf(a00.x + a01.x + b3[o], 0.f);
  r0.y = fmaxf(a00.y + a01.y + b3[o], 0.f);
  r1.x = fmaxf(a10.x + a11.x + b3[o + 1], 0.f);
  r1.y = fmaxf(a10.y + a11.y + b3[o + 1], 0.f);
  *reinterpret_cast<float2*>(&h3[(size_t)o * NB + b]) = r0;
  *reinterpret_cast<float2*>(&h3[(size_t)(o + 1) * NB + b]) = r1;
}

// ---------------------------------------------------------------------------
// K4: fused FC tail. Block = 16 batches (grid 64). Stage h3[120][16] in LDS,
//     fc2+relu into h4L[84][16], then fc3 -> out.
// ---------------------------------------------------------------------------
__global__ __launch_bounds__(256) void k_fctail(const float* __restrict__ h3,
                                                const float* __restrict__ fc2w,
                                                const float* __restrict__ fc2b,
                                                const float* __restrict__ fc3w,
                                                const float* __restrict__ fc3b,
                                                float* __restrict__ out) {
  const int b0 = blockIdx.x * 16;
  const int tid = threadIdx.x;
  __shared__ float h3L[120 * 16];
  __shared__ float h4L[84 * 16];

  for (int t = tid; t < 120 * 16; t += 256) {
    const int k = t >> 4, bb = t & 15;
    h3L[t] = h3[(size_t)k * NB + b0 + bb];
  }
  __syncthreads();

  const int bb = tid & 15;
  {
    const int jbase = tid >> 4;          // 0..15
#pragma unroll
    for (int jr = 0; jr < 6; ++jr) {     // 16*6 = 96 >= 84
      const int j = jbase + jr * 16;
      if (j < 84) {
        const float* __restrict__ wp = fc2w + (size_t)j * 120;
        float a0 = 0.f, a1 = 0.f;
#pragma unroll
        for (int k = 0; k < 120; k += 2) {
          a0 = fmaf(h3L[(k + 0) * 16 + bb], wp[k + 0], a0);
          a1 = fmaf(h3L[(k + 1) * 16 + bb], wp[k + 1], a1);
        }
        h4L[j * 16 + bb] = fmaxf(a0 + a1 + fc2b[j], 0.f);
      }
    }
  }
  __syncthreads();

  if (tid < 160) {
    const int i = tid >> 4;              // 0..9
    const float* __restrict__ wp = fc3w + (size_t)i * 84;
    float a0 = 0.f, a1 = 0.f;
#pragma unroll
    for (int j = 0; j < 84; j += 2) {
      a0 = fmaf(h4L[(j + 0) * 16 + bb], wp[j + 0], a0);
      a1 = fmaf(h4L[(j + 1) * 16 + bb], wp[j + 1], a1);
    }
    out[(size_t)(b0 + bb) * 10 + i] = a0 + a1 + fc3b[i];
  }
}

// ---------------------------------------------------------------------------
extern "C" void kernel_launch(void* const* d_in, const int* in_sizes, int n_in,
                              void* d_out, int out_size, void* d_ws, size_t ws_size,
                              hipStream_t stream) {
  const float* x    = (const float*)d_in[0];
  const float* w1   = (const float*)d_in[1];
  const float* b1   = (const float*)d_in[2];
  const float* w2   = (const float*)d_in[3];
  const float* b2   = (const float*)d_in[4];
  const float* w3   = (const float*)d_in[5];
  const float* b3   = (const float*)d_in[6];
  const float* fc2w = (const float*)d_in[7];
  const float* fc2b = (const float*)d_in[8];
  const float* fc3w = (const float*)d_in[9];
  const float* fc3b = (const float*)d_in[10];
  float* out = (float*)d_out;

  float* ws = (float*)d_ws;
  float* xT = ws;                         // 3*32*32*1024  = 3,145,728 f
  float* h1 = xT + 3145728;               // 6*14*14*1024  = 1,204,224 f
  float* h2 = h1 + 1204224;               // 16*5*5*1024   =   409,600 f
  float* h3 = h2 + 409600;                // 120*1024      =   122,880 f  (~19 MB)

  k_transpose<<<dim3(48, 16), 256, 0, stream>>>(x, xT);
  k_conv1<<<dim3(784), 128, 0, stream>>>(xT, w1, b1, h1);
  k_conv2<<<dim3(800), 128, 0, stream>>>(h1, w2, b2, h2);
  k_conv3<<<dim3(240), 128, 0, stream>>>(h2, w3, b3, h3);
  k_fctail<<<dim3(64), 256, 0, stream>>>(h3, fc2w, fc2b, fc3w, fc3b, out);
}